// Round 7
// baseline (284.456 us; speedup 1.0000x reference)
//
#include <hip/hip_runtime.h>

typedef _Float16 half8 __attribute__((ext_vector_type(8)));
typedef float f32x4 __attribute__((ext_vector_type(4)));
typedef int int4v __attribute__((ext_vector_type(4)));

#define ROWS 64
#define HP 136                  // h row pitch (halfs): 128 + 8 pad
#define HBUFSZ (ROWS * HP)
#define LOG2E 1.442695041f
#define MFMA(a,b,c) __builtin_amdgcn_mfma_f32_16x16x32_f16((a),(b),(c),0,0,0)
#define SCHED __builtin_amdgcn_sched_barrier(0)

__global__ __launch_bounds__(512, 2)
void traj_gru(const float* __restrict__ history,
              const float* __restrict__ w_ih, const float* __restrict__ w_hh,
              const float* __restrict__ b_ih, const float* __restrict__ b_hh,
              const float* __restrict__ w1, const float* __restrict__ b1,
              const float* __restrict__ w2, const float* __restrict__ b2,
              float* __restrict__ out)
{
    __shared__ __align__(16) _Float16 hbuf[2 * HBUFSZ];     // 34,816 B (a1 aliases dead half)
    __shared__ __align__(16) _Float16 xhist[50 * ROWS * 6]; // 38,400 B compact [t][row][6]
    __shared__ __align__(16) _Float16 xdec[ROWS * 8];       //  1,024 B
    __shared__ __align__(16) _Float16 w2f[4 * 4 * 16 * 8];  //  4,096 B => 78,336 total

    const int tid  = threadIdx.x;
    const int wave = tid >> 6;                // 0..7, owns 16 gate-cols per gate
    const int lane = tid & 63;
    const int ln16 = lane & 15;
    const int q    = lane >> 4;
    const int sw   = ln16 & 3;                // read-side K-block swizzle
    const int rowbase = blockIdx.x * ROWS;
    const int cbase = wave * 16;
    const int bblk  = wave >> 1;              // write-side swizzle params
    const int colin = ((wave & 1) << 4) | ln16;

    // ---- init LDS ----
    for (int i = tid; i < 2 * HBUFSZ; i += 512) hbuf[i] = (_Float16)0;
    for (int i = tid; i < ROWS * 8; i += 512) xdec[i] = (_Float16)0;
    for (int i = tid; i < 4 * 4 * 16 * 8; i += 512) w2f[i] = (_Float16)0;
    __syncthreads();
    for (int idx = tid; idx < ROWS * 300; idx += 512) {
        int r = idx / 300, rem = idx - r * 300;
        int t = rem / 6, c = rem - t * 6;
        xhist[(t * ROWS + r) * 6 + c] = (_Float16)history[(rowbase + r) * 300 + rem];
    }
    if (tid < ROWS) xdec[tid * 8 + 6] = (_Float16)1.0f;     // decoder bias lane
    for (int idx = tid; idx < 6 * 128; idx += 512) {        // w2 -> B-frag layout
        int n = idx >> 7, k = idx & 127;
        int kt = k >> 5, qq = (k >> 3) & 3, j = k & 7;
        w2f[((kt * 4 + qq) * 16 + n) * 8 + j] = (_Float16)w2[n * 128 + k];
    }

    // ---- persistent B fragments, gate weights pre-scaled ----
    // r,z: -log2e (sigmoid = rcp(1+exp2)); n: -2log2e (tanh = 2rcp-1)
    half8 Bh[3][4];
    #pragma unroll
    for (int g = 0; g < 3; ++g) {
        float sc = (g < 2) ? -LOG2E : -2.0f * LOG2E;
        #pragma unroll
        for (int kt = 0; kt < 4; ++kt) {
            int n = g * 128 + cbase + ln16;
            const float* p = w_hh + n * 128 + kt * 32 + q * 8;
            half8 v;
            #pragma unroll
            for (int j = 0; j < 8; ++j) v[j] = (_Float16)(p[j] * sc);
            Bh[g][kt] = v;
        }
    }
    half8 Bi[3];
    #pragma unroll
    for (int g = 0; g < 3; ++g) {
        float sc = (g < 2) ? -LOG2E : -2.0f * LOG2E;
        int n = g * 128 + cbase + ln16;
        half8 v;
        #pragma unroll
        for (int j = 0; j < 8; ++j) v[j] = (_Float16)0.0f;
        if (q == 0) {
            #pragma unroll
            for (int j = 0; j < 6; ++j) v[j] = (_Float16)(w_ih[n * 6 + j] * sc);
        }
        Bi[g] = v;
    }
    // biases -> accumulator-init constants (pre-scaled)
    const float brr = (b_ih[      cbase + ln16] + b_hh[      cbase + ln16]) * (-LOG2E);
    const float brz = (b_ih[128 + cbase + ln16] + b_hh[128 + cbase + ln16]) * (-LOG2E);
    const float bin = b_ih[256 + cbase + ln16] * (-2.0f * LOG2E);
    const float bhn = b_hh[256 + cbase + ln16] * (-2.0f * LOG2E);
    half8 Bw1[4];
    #pragma unroll
    for (int kt = 0; kt < 4; ++kt) {
        int n = cbase + ln16;
        const float* p = w1 + n * 128 + kt * 32 + q * 8;
        half8 v;
        #pragma unroll
        for (int j = 0; j < 8; ++j) v[j] = (_Float16)p[j];
        Bw1[kt] = v;
    }
    const float b1r = b1[cbase + ln16];
    const float b2r = (ln16 < 6) ? b2[ln16] : 0.0f;

    float hp[4][4] = {};   // h_prev per chunk (C-layout, step-invariant)

    __syncthreads();

    // ---- GRU step: gates(c) pinned-interleaved with MFMAs(c+1) via sched_barrier ----
    auto gru_step = [&](int p, int t, bool enc) {
        const _Float16* hb = hbuf + p * HBUFSZ;
        _Float16*       hn = hbuf + (p ^ 1) * HBUFSZ;
        half8 Ah[2][4], Ax[2];
        f32x4 ar[2], az[2], ahh[2], an[2];

        auto loadA = [&](int c, int buf) {
            const _Float16* rp = hb + (c * 16 + ln16) * HP;
            #pragma unroll
            for (int kt = 0; kt < 4; ++kt)
                Ah[buf][kt] = *(const half8*)(rp + ((kt ^ sw) << 5) + q * 8);
            // branchless x-tile: all quads read broadcast addresses; q>=1 lanes
            // hold junk that is annihilated by the zero rows of the B-side frag.
            if (enc) {
                const int* xi = (const int*)xhist;
                int base = (t * ROWS + c * 16 + ln16) * 3;
                int4v d = { xi[base], xi[base + 1], xi[base + 2], 0x3C00 }; // fp16 1.0 bias
                Ax[buf] = __builtin_bit_cast(half8, d);
            } else {
                Ax[buf] = *(const half8*)(xdec + (c * 16 + ln16) * 8);
            }
        };
        auto initAcc = [&](int buf) {
            ar[buf]  = f32x4{brr, brr, brr, brr};
            az[buf]  = f32x4{brz, brz, brz, brz};
            ahh[buf] = f32x4{bhn, bhn, bhn, bhn};
            an[buf]  = f32x4{bin, bin, bin, bin};
        };
        auto mfmaK = [&](int buf, int kt) {
            ar[buf]  = MFMA(Ah[buf][kt], Bh[0][kt], ar[buf]);
            az[buf]  = MFMA(Ah[buf][kt], Bh[1][kt], az[buf]);
            ahh[buf] = MFMA(Ah[buf][kt], Bh[2][kt], ahh[buf]);
        };
        auto mfmaX = [&](int buf) {
            ar[buf] = MFMA(Ax[buf], Bi[0], ar[buf]);
            az[buf] = MFMA(Ax[buf], Bi[1], az[buf]);
            an[buf] = MFMA(Ax[buf], Bi[2], an[buf]);
        };
        auto gate1 = [&](int c, int cb, int i) {
            float r = __builtin_amdgcn_rcpf(1.0f + __builtin_amdgcn_exp2f(ar[cb][i]));
            float z = __builtin_amdgcn_rcpf(1.0f + __builtin_amdgcn_exp2f(az[cb][i]));
            float tt = an[cb][i] + r * ahh[cb][i];           // bhn folded into init
            float n = 2.0f * __builtin_amdgcn_rcpf(1.0f + __builtin_amdgcn_exp2f(tt)) - 1.0f;
            float h = n + z * (hp[c][i] - n);
            hp[c][i] = h;
            hn[(c * 16 + q * 4 + i) * HP + ((bblk ^ i) << 5) + colin] = (_Float16)h;
        };

        // prologue: chunk 0 MFMAs
        loadA(0, 0); initAcc(0);
        SCHED;
        #pragma unroll
        for (int kt = 0; kt < 4; ++kt) mfmaK(0, kt);
        mfmaX(0);
        SCHED;
        // steady state: {1 gate element} / {3 MFMAs} alternation, pinned
        #pragma unroll
        for (int c = 0; c < 3; ++c) {
            const int cb = c & 1, nb = cb ^ 1;
            loadA(c + 1, nb); initAcc(nb);
            SCHED;
            gate1(c, cb, 0);  SCHED;  mfmaK(nb, 0);  SCHED;
            gate1(c, cb, 1);  SCHED;  mfmaK(nb, 1);  SCHED;
            gate1(c, cb, 2);  SCHED;  mfmaK(nb, 2);  SCHED;
            gate1(c, cb, 3);  SCHED;  mfmaK(nb, 3); mfmaX(nb);  SCHED;
        }
        gate1(3, 1, 0); gate1(3, 1, 1); gate1(3, 1, 2); gate1(3, 1, 3);
        __syncthreads();
    };

    auto head_step = [&](int f, int p) {
        const _Float16* hb = hbuf + p * HBUFSZ;
        _Float16*       a1 = hbuf + (p ^ 1) * HBUFSZ;   // dead ping-pong half
        half8 Ah[2][4];
        f32x4 aa[2];
        auto loadA = [&](int c, int buf) {
            const _Float16* rp = hb + (c * 16 + ln16) * HP;
            #pragma unroll
            for (int kt = 0; kt < 4; ++kt)
                Ah[buf][kt] = *(const half8*)(rp + ((kt ^ sw) << 5) + q * 8);
        };
        auto mfh = [&](int buf) {
            f32x4 a = {0,0,0,0};
            #pragma unroll
            for (int kt = 0; kt < 4; ++kt) a = MFMA(Ah[buf][kt], Bw1[kt], a);
            aa[buf] = a;
        };
        auto relu4 = [&](int c, int cb) {
            #pragma unroll
            for (int i = 0; i < 4; ++i) {
                float v = aa[cb][i] + b1r;
                v = v > 0.0f ? v : 0.0f;
                a1[(c * 16 + q * 4 + i) * HP + ((bblk ^ i) << 5) + colin] = (_Float16)v;
            }
        };
        loadA(0, 0); mfh(0);
        SCHED;
        #pragma unroll
        for (int c = 0; c < 3; ++c) {
            const int cb = c & 1;
            loadA(c + 1, cb ^ 1);
            SCHED;
            relu4(c, cb);
            SCHED;
            mfh(cb ^ 1);
            SCHED;
        }
        relu4(3, 1);
        __syncthreads();
        if (wave < 4) {   // 4 M-tiles of the 64x6 output
            const _Float16* rp = a1 + (wave * 16 + ln16) * HP;
            f32x4 o = {0,0,0,0};
            #pragma unroll
            for (int kt = 0; kt < 4; ++kt) {
                half8 Aa = *(const half8*)(rp + ((kt ^ sw) << 5) + q * 8);
                half8 Bw = *(const half8*)&w2f[((kt * 4 + q) * 16 + ln16) * 8];
                o = MFMA(Aa, Bw, o);
            }
            if (ln16 < 6) {
                #pragma unroll
                for (int i = 0; i < 4; ++i) {
                    int row = wave * 16 + q * 4 + i;
                    float v = o[i] + b2r;
                    out[(rowbase + row) * 180 + f * 6 + ln16] = v;
                    xdec[row * 8 + ln16] = (_Float16)v;   // next decoder x
                }
            }
        }
        __syncthreads();
    };

    int p = 0;
    #pragma unroll 1
    for (int t = 0; t < 50; ++t) { gru_step(p, t, true); p ^= 1; }
    // decoder x_0 = history[:, 49]
    for (int idx = tid; idx < ROWS * 6; idx += 512) {
        int r = idx / 6, c = idx - r * 6;
        xdec[r * 8 + c] = xhist[(49 * ROWS + r) * 6 + c];
    }
    __syncthreads();
    #pragma unroll 1
    for (int f = 0; f < 30; ++f) {
        gru_step(p, 0, false);
        p ^= 1;
        head_step(f, p);
    }
}

extern "C" void kernel_launch(void* const* d_in, const int* in_sizes, int n_in,
                              void* d_out, int out_size, void* d_ws, size_t ws_size,
                              hipStream_t stream) {
    (void)in_sizes; (void)n_in; (void)d_ws; (void)ws_size; (void)out_size;
    traj_gru<<<dim3(16384 / ROWS), dim3(512), 0, stream>>>(
        (const float*)d_in[0], (const float*)d_in[1], (const float*)d_in[2],
        (const float*)d_in[3], (const float*)d_in[4], (const float*)d_in[5],
        (const float*)d_in[6], (const float*)d_in[7], (const float*)d_in[8],
        (float*)d_out);
}

// Round 9
// 270.265 us; speedup vs baseline: 1.0525x; 1.0525x over previous
//
#include <hip/hip_runtime.h>

typedef _Float16 half8 __attribute__((ext_vector_type(8)));
typedef _Float16 half4 __attribute__((ext_vector_type(4)));
typedef float f32x4 __attribute__((ext_vector_type(4)));
typedef int int4v __attribute__((ext_vector_type(4)));

#define ROWS 64
#define HP 136                  // h row pitch (halfs): 128 + 8 pad; 272 B
#define HBUFSZ (ROWS * HP)
#define LOG2E 1.442695041f
#define MFMA(a,b,c) __builtin_amdgcn_mfma_f32_16x16x32_f16((a),(b),(c),0,0,0)

__global__ __launch_bounds__(512, 2)
void traj_gru(const float* __restrict__ history,
              const float* __restrict__ w_ih, const float* __restrict__ w_hh,
              const float* __restrict__ b_ih, const float* __restrict__ b_hh,
              const float* __restrict__ w1, const float* __restrict__ b1,
              const float* __restrict__ w2, const float* __restrict__ b2,
              float* __restrict__ out)
{
    __shared__ __align__(16) _Float16 hbuf[2 * HBUFSZ];     // 34,816 B; a1 aliases dead half
    __shared__ __align__(16) _Float16 xhist[50 * ROWS * 6]; // 38,400 B compact [t][row][6]
    __shared__ __align__(16) _Float16 xdec[ROWS * 8];       //  1,024 B
    __shared__ __align__(16) _Float16 w2f[4 * 4 * 16 * 8];  //  4,096 B => 78,336 total

    const int tid  = threadIdx.x;
    const int wave = tid >> 6;
    const int lane = tid & 63;
    const int ln16 = lane & 15;
    const int q    = lane >> 4;
    const int sw   = ln16 & 3;               // head-phase2 a1s read swizzle (round-7 pair)
    const int rowbase = blockIdx.x * ROWS;
    const int dbase = wave * 16;             // gru: wave's h-dims; head: wave's a1-dims
    const int bblk  = wave >> 1;             // head a1s write swizzle (round-7 pair)
    const int colin = ((wave & 1) << 4) | ln16;

    // ---- init LDS: zeros first, barrier, then fills ----
    for (int i = tid; i < 2 * HBUFSZ; i += 512) hbuf[i] = (_Float16)0;
    for (int i = tid; i < ROWS * 8; i += 512) xdec[i] = (_Float16)0;
    for (int i = tid; i < 4 * 4 * 16 * 8; i += 512) w2f[i] = (_Float16)0;
    __syncthreads();
    for (int idx = tid; idx < ROWS * 300; idx += 512) {
        int r = idx / 300, rem = idx - r * 300;
        int t = rem / 6, c = rem - t * 6;
        xhist[(t * ROWS + r) * 6 + c] = (_Float16)history[(rowbase + r) * 300 + rem];
    }
    if (tid < ROWS) xdec[tid * 8 + 6] = (_Float16)1.0f;   // decoder bias slot
    for (int idx = tid; idx < 6 * 128; idx += 512) {      // w2 -> B-frag layout (round-7)
        int n = idx >> 7, k = idx & 127;
        int kt = k >> 5, qq = (k >> 3) & 3, j = k & 7;
        w2f[((kt * 4 + qq) * 16 + n) * 8 + j] = (_Float16)w2[n * 128 + k];
    }

    // ---- persistent register fragments ----
    // GRU (transposed): A-side = weights, m=ln16 -> dim dbase+ln16, k=kt*32+q*8+j
    // r,z pre-scaled by -log2e (sigmoid = rcp(1+exp2)); n by -2log2e (tanh = 2rcp-1)
    half8 Wg[3][4];
    #pragma unroll
    for (int g = 0; g < 3; ++g) {
        float sc = (g < 2) ? -LOG2E : -2.0f * LOG2E;
        #pragma unroll
        for (int kt = 0; kt < 4; ++kt) {
            const float* p = w_hh + (g * 128 + dbase + ln16) * 128 + kt * 32 + q * 8;
            half8 v;
            #pragma unroll
            for (int j = 0; j < 8; ++j) v[j] = (_Float16)(p[j] * sc);
            Wg[g][kt] = v;
        }
    }
    half8 Wx[3];     // A-side x-weights: q==0 rows k<6; bias via acc init
    #pragma unroll
    for (int g = 0; g < 3; ++g) {
        float sc = (g < 2) ? -LOG2E : -2.0f * LOG2E;
        half8 v;
        #pragma unroll
        for (int j = 0; j < 8; ++j) v[j] = (_Float16)0.0f;
        if (q == 0) {
            #pragma unroll
            for (int j = 0; j < 6; ++j) v[j] = (_Float16)(w_ih[(g * 128 + dbase + ln16) * 6 + j] * sc);
        }
        Wx[g] = v;
    }
    // gru biases -> acc init, element i -> C row = dim dbase+q*4+i
    f32x4 brr, brz, bin, bhn;
    #pragma unroll
    for (int i = 0; i < 4; ++i) {
        int d = dbase + q * 4 + i;
        brr[i] = (b_ih[d]       + b_hh[d]      ) * (-LOG2E);
        brz[i] = (b_ih[128 + d] + b_hh[128 + d]) * (-LOG2E);
        bin[i] = b_ih[256 + d] * (-2.0f * LOG2E);
        bhn[i] = b_hh[256 + d] * (-2.0f * LOG2E);
    }
    // HEAD (round-7 orientation): B-side w1, n=ln16 -> a1-dim dbase+ln16
    half8 Bw1[4];
    #pragma unroll
    for (int kt = 0; kt < 4; ++kt) {
        const float* p = w1 + (dbase + ln16) * 128 + kt * 32 + q * 8;
        half8 v;
        #pragma unroll
        for (int j = 0; j < 8; ++j) v[j] = (_Float16)p[j];
        Bw1[kt] = v;
    }
    const float b1r = b1[dbase + ln16];
    const float b2r = (ln16 < 6) ? b2[ln16] : 0.0f;

    float hp[4][4] = {};  // h_prev: lane holds (batch=c*16+ln16, dim=dbase+q*4+i)

    __syncthreads();

    // ---- transposed GRU step: C[dim][batch], contiguous half4 h-writes ----
    auto gru_step = [&](int p, int t, bool enc) {
        const _Float16* hb = hbuf + p * HBUFSZ;
        _Float16*       hn = hbuf + (p ^ 1) * HBUFSZ;
        half8 Bf[2][4], Bx[2];
        f32x4 ar[2], az[2], ahh[2], an[2];

        auto loadB = [&](int c, int buf) {
            const _Float16* rp = hb + (c * 16 + ln16) * HP;
            #pragma unroll
            for (int kt = 0; kt < 4; ++kt)
                Bf[buf][kt] = *(const half8*)(rp + kt * 32 + q * 8);
            if (enc) {   // clean broadcast: registers only, no junk, no overread
                const int* xi = (const int*)xhist;
                int base = (t * ROWS + c * 16 + ln16) * 3;
                int4v d = { xi[base], xi[base + 1], xi[base + 2], 0x3C00 }; // [x0..x5,1,0]
                Bx[buf] = __builtin_bit_cast(half8, d);
            } else {
                Bx[buf] = *(const half8*)(xdec + (c * 16 + ln16) * 8);      // broadcast
            }
        };
        auto mfmas = [&](int buf) {
            f32x4 r = brr, z = brz, hh = bhn, n = bin;
            #pragma unroll
            for (int kt = 0; kt < 4; ++kt) {
                r  = MFMA(Wg[0][kt], Bf[buf][kt], r);
                z  = MFMA(Wg[1][kt], Bf[buf][kt], z);
                hh = MFMA(Wg[2][kt], Bf[buf][kt], hh);
            }
            r = MFMA(Wx[0], Bx[buf], r);
            z = MFMA(Wx[1], Bx[buf], z);
            n = MFMA(Wx[2], Bx[buf], n);
            ar[buf] = r; az[buf] = z; ahh[buf] = hh; an[buf] = n;
        };
        auto gates = [&](int c, int cb) {
            half4 hv;
            #pragma unroll
            for (int i = 0; i < 4; ++i) {
                float r = __builtin_amdgcn_rcpf(1.0f + __builtin_amdgcn_exp2f(ar[cb][i]));
                float z = __builtin_amdgcn_rcpf(1.0f + __builtin_amdgcn_exp2f(az[cb][i]));
                float tt = an[cb][i] + r * ahh[cb][i];
                float n = 2.0f * __builtin_amdgcn_rcpf(1.0f + __builtin_amdgcn_exp2f(tt)) - 1.0f;
                float h = n + z * (hp[c][i] - n);
                hp[c][i] = h;
                hv[i] = (_Float16)h;
            }
            *(half4*)(hn + (c * 16 + ln16) * HP + dbase + q * 4) = hv;
        };

        loadB(0, 0); mfmas(0);
        #pragma unroll
        for (int c = 0; c < 4; ++c) {
            const int cb = c & 1;
            if (c < 3) { loadB(c + 1, cb ^ 1); mfmas(cb ^ 1); }
            gates(c, cb);
        }
        __syncthreads();
    };

    // ---- head step: byte-for-byte round-7 (verified), h read is plain layout ----
    auto head_step = [&](int f, int p) {
        const _Float16* hb = hbuf + p * HBUFSZ;
        _Float16*       a1 = hbuf + (p ^ 1) * HBUFSZ;   // dead ping-pong half
        half8 Ah[2][4];
        f32x4 aa[2];
        auto loadA = [&](int c, int buf) {
            const _Float16* rp = hb + (c * 16 + ln16) * HP;
            #pragma unroll
            for (int kt = 0; kt < 4; ++kt)
                Ah[buf][kt] = *(const half8*)(rp + kt * 32 + q * 8);   // plain [batch][dim]
        };
        auto mfh = [&](int buf) {
            f32x4 a = {0,0,0,0};
            #pragma unroll
            for (int kt = 0; kt < 4; ++kt) a = MFMA(Ah[buf][kt], Bw1[kt], a);
            aa[buf] = a;
        };
        auto relu4 = [&](int c, int cb) {
            #pragma unroll
            for (int i = 0; i < 4; ++i) {
                float v = aa[cb][i] + b1r;
                v = v > 0.0f ? v : 0.0f;
                a1[(c * 16 + q * 4 + i) * HP + ((bblk ^ i) << 5) + colin] = (_Float16)v;
            }
        };
        loadA(0, 0); mfh(0);
        #pragma unroll
        for (int c = 0; c < 4; ++c) {
            const int cb = c & 1;
            if (c < 3) { loadA(c + 1, cb ^ 1); mfh(cb ^ 1); }
            relu4(c, cb);
        }
        __syncthreads();
        if (wave < 4) {   // round-7 phase 2: A=a1 (m=batch), B=w2f (n=out-dim)
            const _Float16* rp = a1 + (wave * 16 + ln16) * HP;
            f32x4 o = {0,0,0,0};
            #pragma unroll
            for (int kt = 0; kt < 4; ++kt) {
                half8 Aa = *(const half8*)(rp + ((kt ^ sw) << 5) + q * 8);
                half8 Bw = *(const half8*)&w2f[((kt * 4 + q) * 16 + ln16) * 8];
                o = MFMA(Aa, Bw, o);
            }
            if (ln16 < 6) {
                #pragma unroll
                for (int i = 0; i < 4; ++i) {
                    int row = wave * 16 + q * 4 + i;
                    float v = o[i] + b2r;
                    out[(rowbase + row) * 180 + f * 6 + ln16] = v;
                    xdec[row * 8 + ln16] = (_Float16)v;   // next decoder x (slots 0..5)
                }
            }
        }
        __syncthreads();
    };

    int p = 0;
    #pragma unroll 1
    for (int t = 0; t < 50; ++t) { gru_step(p, t, true); p ^= 1; }
    #pragma unroll 1
    for (int f = 0; f < 30; ++f) {
        gru_step(p, f == 0 ? 49 : 0, f == 0);   // f=0: x = history[:,49]
        p ^= 1;
        head_step(f, p);
    }
}

extern "C" void kernel_launch(void* const* d_in, const int* in_sizes, int n_in,
                              void* d_out, int out_size, void* d_ws, size_t ws_size,
                              hipStream_t stream) {
    (void)in_sizes; (void)n_in; (void)d_ws; (void)ws_size; (void)out_size;
    traj_gru<<<dim3(16384 / ROWS), dim3(512), 0, stream>>>(
        (const float*)d_in[0], (const float*)d_in[1], (const float*)d_in[2],
        (const float*)d_in[3], (const float*)d_in[4], (const float*)d_in[5],
        (const float*)d_in[6], (const float*)d_in[7], (const float*)d_in[8],
        (float*)d_out);
}